// Round 3
// baseline (1417.845 us; speedup 1.0000x reference)
//
#include <hip/hip_runtime.h>

// ---------------- constants ----------------
constexpr int Bn = 4;      // batch
constexpr int Sn = 512;    // seq
constexpr int Hn = 1024;   // hidden
constexpr int NSIM = 32;
constexpr int KF = 3;
constexpr int NR = NSIM * Bn;   // 128 (sim,batch) rows, r = sim*4 + b

__device__ __forceinline__ float gelu_f(float x) {
    return 0.5f * x * (1.0f + erff(x * 0.70710678118654752440f));
}

// ---------------- threefry2x32 (JAX-exact) ----------------
__device__ __forceinline__ unsigned rotl32(unsigned v, int n) {
    return (v << n) | (v >> (32 - n));
}

__device__ __forceinline__ void tf2x32(unsigned k0, unsigned k1,
                                       unsigned x0, unsigned x1,
                                       unsigned& o0, unsigned& o1) {
    unsigned ks2 = k0 ^ k1 ^ 0x1BD11BDAu;
    x0 += k0; x1 += k1;
    // group 1 (rot set 0)
    x0 += x1; x1 = rotl32(x1, 13); x1 ^= x0;
    x0 += x1; x1 = rotl32(x1, 15); x1 ^= x0;
    x0 += x1; x1 = rotl32(x1, 26); x1 ^= x0;
    x0 += x1; x1 = rotl32(x1, 6);  x1 ^= x0;
    x0 += k1; x1 += ks2 + 1u;
    // group 2 (rot set 1)
    x0 += x1; x1 = rotl32(x1, 17); x1 ^= x0;
    x0 += x1; x1 = rotl32(x1, 29); x1 ^= x0;
    x0 += x1; x1 = rotl32(x1, 16); x1 ^= x0;
    x0 += x1; x1 = rotl32(x1, 24); x1 ^= x0;
    x0 += ks2; x1 += k0 + 2u;
    // group 3 (rot set 0)
    x0 += x1; x1 = rotl32(x1, 13); x1 ^= x0;
    x0 += x1; x1 = rotl32(x1, 15); x1 ^= x0;
    x0 += x1; x1 = rotl32(x1, 26); x1 ^= x0;
    x0 += x1; x1 = rotl32(x1, 6);  x1 ^= x0;
    x0 += k0; x1 += k1 + 3u;
    // group 4 (rot set 1)
    x0 += x1; x1 = rotl32(x1, 17); x1 ^= x0;
    x0 += x1; x1 = rotl32(x1, 29); x1 ^= x0;
    x0 += x1; x1 = rotl32(x1, 16); x1 ^= x0;
    x0 += x1; x1 = rotl32(x1, 24); x1 ^= x0;
    x0 += k1; x1 += ks2 + 4u;
    // group 5 (rot set 0)
    x0 += x1; x1 = rotl32(x1, 13); x1 ^= x0;
    x0 += x1; x1 = rotl32(x1, 15); x1 ^= x0;
    x0 += x1; x1 = rotl32(x1, 26); x1 ^= x0;
    x0 += x1; x1 = rotl32(x1, 6);  x1 ^= x0;
    x0 += ks2; x1 += k0 + 5u;
    o0 = x0; o1 = x1;
}

__device__ __forceinline__ float gumbel_from_bits(unsigned bits) {
    // uniform: u = bitcast((bits>>9)|0x3F800000) - 1;  r = max(tiny, u*(1-tiny)+tiny)
    // (1-tiny) rounds to 1.0f in fp32, so r = max(tiny, u+tiny)
    float u = __uint_as_float((bits >> 9) | 0x3F800000u) - 1.0f;
    const float TINY = 1.17549435082228750797e-38f;
    float r = fmaxf(TINY, u + TINY);
    // gumbel = -log(-log(r)) with fp32 rounding at each step (correctly-rounded fp32 log)
    float inner = (float)(-log((double)r));
    float g = (float)(-log((double)inner));
    return g;
}

// ---------------- big GEMM: C = act(A@B + bias) [+res], 128x128 tile ----------------
template<int ACT, int RES>
__global__ __launch_bounds__(256) void gemm128(const float* __restrict__ A1,
                                               const float* __restrict__ A2, int K1,
                                               const float* __restrict__ Bm,
                                               const float* __restrict__ bias,
                                               const float* __restrict__ res,
                                               float* __restrict__ C,
                                               int M, int N, int K) {
    __shared__ float As[16][132];
    __shared__ float Bs[16][132];
    const int t = threadIdx.x;
    const int m0 = blockIdx.y * 128, n0 = blockIdx.x * 128;
    const int tm = t >> 4, tn = t & 15;
    float acc[8][8];
#pragma unroll
    for (int i = 0; i < 8; i++)
#pragma unroll
        for (int j = 0; j < 8; j++) acc[i][j] = 0.f;

    const int K2s = K - K1;
    for (int k0 = 0; k0 < K; k0 += 16) {
        {
            int m_l = t >> 1, k_l = (t & 1) * 8;
            int gm = m0 + m_l;
#pragma unroll
            for (int q = 0; q < 2; ++q) {
                int gk = k0 + k_l + q * 4;
                const float* src = (gk < K1) ? (A1 + (size_t)gm * K1 + gk)
                                             : (A2 + (size_t)gm * K2s + (gk - K1));
                float4 v = *(const float4*)src;
                As[k_l + q * 4 + 0][m_l] = v.x;
                As[k_l + q * 4 + 1][m_l] = v.y;
                As[k_l + q * 4 + 2][m_l] = v.z;
                As[k_l + q * 4 + 3][m_l] = v.w;
            }
            int k_b = t >> 4, n_l = (t & 15) * 8;
            const float* srcb = Bm + (size_t)(k0 + k_b) * N + n0 + n_l;
            *(float4*)&Bs[k_b][n_l]     = *(const float4*)srcb;
            *(float4*)&Bs[k_b][n_l + 4] = *(const float4*)(srcb + 4);
        }
        __syncthreads();
#pragma unroll
        for (int kk = 0; kk < 16; ++kk) {
            float a[8], b[8];
            *(float4*)&a[0] = *(float4*)&As[kk][tm * 8];
            *(float4*)&a[4] = *(float4*)&As[kk][tm * 8 + 4];
            *(float4*)&b[0] = *(float4*)&Bs[kk][tn * 8];
            *(float4*)&b[4] = *(float4*)&Bs[kk][tn * 8 + 4];
#pragma unroll
            for (int i = 0; i < 8; i++)
#pragma unroll
                for (int j = 0; j < 8; j++) acc[i][j] = fmaf(a[i], b[j], acc[i][j]);
        }
        __syncthreads();
    }
#pragma unroll
    for (int i = 0; i < 8; i++) {
        int gm = m0 + tm * 8 + i;
#pragma unroll
        for (int j = 0; j < 8; j++) {
            int gn = n0 + tn * 8 + j;
            float v = acc[i][j] + bias[gn];
            if (ACT) v = gelu_f(v);
            if (RES) v += res[(size_t)gm * N + gn];
            C[(size_t)gm * N + gn] = v;
        }
    }
}

// ---------------- thin GEMM (M multiple of 16): C = act(A@B + bias) ----------------
template<int ACT>
__global__ __launch_bounds__(256) void gemm_thin(const float* __restrict__ A,
                                                 const float* __restrict__ Bm,
                                                 const float* __restrict__ bias,
                                                 float* __restrict__ C,
                                                 int M, int N, int K) {
    __shared__ float As[32][17];
    __shared__ float Bs[32][132];
    const int t = threadIdx.x;
    const int m0 = blockIdx.y * 16, n0 = blockIdx.x * 128;
    const int tm = t >> 4, tn = t & 15;
    float acc[8];
#pragma unroll
    for (int j = 0; j < 8; j++) acc[j] = 0.f;

    for (int k0 = 0; k0 < K; k0 += 32) {
        {
            int m_l = t >> 4, k_l = (t & 15) * 2;
            float2 va = *(const float2*)(A + (size_t)(m0 + m_l) * K + k0 + k_l);
            As[k_l][m_l] = va.x;
            As[k_l + 1][m_l] = va.y;
            int k_b = t >> 3, n_l = (t & 7) * 16;
            const float* sb = Bm + (size_t)(k0 + k_b) * N + n0 + n_l;
#pragma unroll
            for (int q = 0; q < 4; q++)
                *(float4*)&Bs[k_b][n_l + 4 * q] = *(const float4*)(sb + 4 * q);
        }
        __syncthreads();
#pragma unroll
        for (int kk = 0; kk < 32; ++kk) {
            float a = As[kk][tm];
            float b[8];
            *(float4*)&b[0] = *(float4*)&Bs[kk][tn * 8];
            *(float4*)&b[4] = *(float4*)&Bs[kk][tn * 8 + 4];
#pragma unroll
            for (int j = 0; j < 8; j++) acc[j] = fmaf(a, b[j], acc[j]);
        }
        __syncthreads();
    }
    int gm = m0 + tm;
#pragma unroll
    for (int j = 0; j < 8; j++) {
        int gn = n0 + tn * 8 + j;
        float v = acc[j] + bias[gn];
        if (ACT) v = gelu_f(v);
        C[(size_t)gm * N + gn] = v;
    }
}

// ---------------- cls head -> sim_counts ----------------
__global__ __launch_bounds__(256) void k_cls(const float* __restrict__ hidden,
                                             const float* __restrict__ Wc1,
                                             const float* __restrict__ bc1,
                                             const float* __restrict__ Wc2,
                                             const float* __restrict__ bc2,
                                             int* __restrict__ cnt) {
    __shared__ float cls[Hn];
    __shared__ float h1[Hn];
    __shared__ float lg[5];
    const int b = blockIdx.x, t = threadIdx.x;
    *(float4*)&cls[t * 4] = *(const float4*)&hidden[(size_t)b * Sn * Hn + t * 4];
    if (t < 5) lg[t] = 0.f;
    __syncthreads();
    float s0 = bc1[t], s1 = bc1[t + 256], s2 = bc1[t + 512], s3 = bc1[t + 768];
    for (int i = 0; i < Hn; ++i) {
        float cv = cls[i];
        const float* wr = Wc1 + (size_t)i * Hn + t;
        s0 = fmaf(cv, wr[0], s0);
        s1 = fmaf(cv, wr[256], s1);
        s2 = fmaf(cv, wr[512], s2);
        s3 = fmaf(cv, wr[768], s3);
    }
    h1[t] = gelu_f(s0); h1[t + 256] = gelu_f(s1);
    h1[t + 512] = gelu_f(s2); h1[t + 768] = gelu_f(s3);
    __syncthreads();
    float p[5] = {0.f, 0.f, 0.f, 0.f, 0.f};
    for (int i = t; i < Hn; i += 256) {
        float hv = h1[i];
#pragma unroll
        for (int c = 0; c < 5; c++) p[c] = fmaf(hv, Wc2[i * 5 + c], p[c]);
    }
#pragma unroll
    for (int c = 0; c < 5; c++) atomicAdd(&lg[c], p[c]);
    __syncthreads();
    if (t == 0) {
        int best = 0;
        float bv = lg[0] + bc2[0];
        for (int c = 1; c < 5; c++) {
            float v = lg[c] + bc2[c];
            if (v > bv) { bv = v; best = c; }   // first max wins (argmax semantics)
        }
        const int opts[5] = {10, 10, 16, 24, 32};
        cnt[b] = opts[best];
    }
}

// ---------------- Wp2 row-mean + bp2 mean ----------------
__global__ __launch_bounds__(256) void k_wp2mean(const float* __restrict__ Wp2,
                                                 const float* __restrict__ bp2,
                                                 float* __restrict__ wp2m,
                                                 float* __restrict__ bp2m) {
    const int t = threadIdx.x;
    const int row = blockIdx.x * 4 + (t >> 6);
    const int lane = t & 63;
    float s = 0.f;
    const float* wr = Wp2 + (size_t)row * Hn;
    for (int j = lane; j < Hn; j += 64) s += wr[j];
    for (int o = 32; o > 0; o >>= 1) s += __shfl_down(s, o, 64);
    if (lane == 0) wp2m[row] = s * (1.0f / (float)Hn);
    if (blockIdx.x == 0) {
        __shared__ float red[256];
        float q = 0.f;
        for (int j = t; j < Hn; j += 256) q += bp2[j];
        red[t] = q;
        __syncthreads();
        for (int st = 128; st > 0; st >>= 1) {
            if (t < st) red[t] += red[t + st];
            __syncthreads();
        }
        if (t == 0) bp2m[0] = red[0] * (1.0f / (float)Hn);
    }
}

// ---------------- focus scores = p1 . wp2m + bp2m (masked) ----------------
__global__ __launch_bounds__(256) void k_focus(const float* __restrict__ p1,
                                               const float* __restrict__ wp2m,
                                               const float* __restrict__ bp2m,
                                               const int* __restrict__ amask,
                                               float* __restrict__ focus) {
    const int t = threadIdx.x;
    const int row = blockIdx.x * 4 + (t >> 6);   // b*512+s
    const int lane = t & 63;
    float s = 0.f;
    const float* pr = p1 + (size_t)row * Hn;
    for (int j = lane; j < Hn; j += 64) s = fmaf(pr[j], wp2m[j], s);
    for (int o = 32; o > 0; o >>= 1) s += __shfl_down(s, o, 64);
    if (lane == 0) {
        float v = s + bp2m[0];
        if (amask[row] == 0) v = -1000000000.0f;
        focus[row] = v;
    }
}

// ---------------- root mean over S ----------------
__global__ __launch_bounds__(256) void k_rootmean(const float* __restrict__ hidden,
                                                  float* __restrict__ rm) {
    const int g = blockIdx.x * 256 + threadIdx.x;   // b*1024 + h
    const int b = g >> 10, h = g & 1023;
    float s = 0.f;
    for (int ss = 0; ss < Sn; ++ss) s += hidden[((size_t)b * Sn + ss) * Hn + h];
    rm[g] = s * (1.0f / (float)Sn);
}

// ---------------- m init: copy rm per (sim,b) ----------------
__global__ __launch_bounds__(256) void k_minit(const float* __restrict__ rm,
                                               float* __restrict__ m) {
    const int g = blockIdx.x * 256 + threadIdx.x;   // r*1024 + h
    const int h = g & 1023, r = g >> 10, b = r & 3;
    m[g] = rm[b * Hn + h];
}

// ---------------- gumbel + top-3 per (sim, b) — PARTITIONABLE threefry ----------------
__global__ __launch_bounds__(256) void k_gumbel_topk(const float* __restrict__ focus,
                                                     int* __restrict__ fpos) {
    __shared__ float sv[Sn];
    __shared__ float rv[256];
    __shared__ int ri[256];
    const int t = threadIdx.x;
    const int blk = blockIdx.x;          // r = sim*4 + b
    const int sim = blk >> 2, b = blk & 3;
    // partitionable split: child key[sim] = threefry2x32(key(42)=(0,42); x0=0, x1=sim) -> (o0,o1)
    unsigned khi, klo;
    tf2x32(0u, 42u, 0u, (unsigned)sim, khi, klo);
#pragma unroll
    for (int q = 0; q < 2; q++) {
        int p = t + q * 256;
        int i = b * Sn + p;              // flat index into (4,512) gumbel draw
        // partitionable random_bits(32): u64 count i -> cipher(x0=hi32=0, x1=lo32=i), bits = o0^o1
        unsigned o0, o1;
        tf2x32(khi, klo, 0u, (unsigned)i, o0, o1);
        sv[p] = focus[b * Sn + p] + gumbel_from_bits(o0 ^ o1);
    }
    __syncthreads();
    for (int k = 0; k < KF; k++) {
        float v1 = sv[t], v2 = sv[t + 256];
        float bv; int bi;
        if (v2 > v1) { bv = v2; bi = t + 256; } else { bv = v1; bi = t; }
        rv[t] = bv; ri[t] = bi;
        __syncthreads();
        for (int s2 = 128; s2 > 0; s2 >>= 1) {
            if (t < s2) {
                float ov = rv[t + s2]; int oi = ri[t + s2];
                if (ov > rv[t] || (ov == rv[t] && oi < ri[t])) { rv[t] = ov; ri[t] = oi; }
            }
            __syncthreads();
        }
        if (t == 0) {
            fpos[blk * KF + k] = ri[0];
            sv[ri[0]] = -INFINITY;
        }
        __syncthreads();
    }
}

// ---------------- assemble TI = [m_r , root[b, pos_k]] ----------------
__global__ __launch_bounds__(256) void k_ti(const float* __restrict__ m,
                                            const float* __restrict__ hidden,
                                            const int* __restrict__ fpos, int kstep,
                                            float* __restrict__ TI) {
    const int r = blockIdx.x, t = threadIdx.x, b = r & 3;
    const int pos = fpos[r * KF + kstep];
    const float* rootrow = hidden + ((size_t)b * Sn + pos) * Hn;
    float* dst = TI + (size_t)r * (2 * Hn);
    int j = t * 4;
    *(float4*)&dst[j] = *(const float4*)&m[(size_t)r * Hn + j];
    *(float4*)&dst[Hn + j] = *(const float4*)&rootrow[j];
}

// ---------------- m += (new - prev)/S with collision-aware prev ----------------
__global__ __launch_bounds__(256) void k_mupdate(float* __restrict__ m,
                                                 const float* __restrict__ newbuf,
                                                 const float* __restrict__ hidden,
                                                 const int* __restrict__ fpos, int kstep) {
    const int r = blockIdx.x, t = threadIdx.x, b = r & 3;
    const int pos = fpos[r * KF + kstep];
    const float* nrow = newbuf + ((size_t)kstep * NR + r) * Hn;
    const float* prev = hidden + ((size_t)b * Sn + pos) * Hn;
    for (int kp = kstep - 1; kp >= 0; --kp) {
        if (fpos[r * KF + kp] == pos) { prev = newbuf + ((size_t)kp * NR + r) * Hn; break; }
    }
    int j = t * 4;
    float4 nv = *(const float4*)&nrow[j];
    float4 pv = *(const float4*)&prev[j];
    float4 mv = *(const float4*)&m[(size_t)r * Hn + j];
    const float inv = 1.0f / (float)Sn;
    mv.x += (nv.x - pv.x) * inv;
    mv.y += (nv.y - pv.y) * inv;
    mv.z += (nv.z - pv.z) * inv;
    mv.w += (nv.w - pv.w) * inv;
    *(float4*)&m[(size_t)r * Hn + j] = mv;
}

// ---------------- assemble VA = [rm[b], m_r] ----------------
__global__ __launch_bounds__(256) void k_va(const float* __restrict__ rm,
                                            const float* __restrict__ m,
                                            float* __restrict__ VA) {
    const int r = blockIdx.x, t = threadIdx.x, b = r & 3;
    float* dst = VA + (size_t)r * (2 * Hn);
    int j = t * 4;
    *(float4*)&dst[j] = *(const float4*)&rm[b * Hn + j];
    *(float4*)&dst[Hn + j] = *(const float4*)&m[(size_t)r * Hn + j];
}

// ---------------- val = A1 . Wa2 + ba2 -> w = sigmoid ----------------
__global__ __launch_bounds__(256) void k_val(const float* __restrict__ A1,
                                             const float* __restrict__ Wa2,
                                             const float* __restrict__ ba2,
                                             float* __restrict__ w) {
    const int t = threadIdx.x;
    const int r = blockIdx.x * 4 + (t >> 6);
    const int lane = t & 63;
    float s = 0.f;
    const float* ar = A1 + (size_t)r * Hn;
    for (int j = lane; j < Hn; j += 64) s = fmaf(ar[j], Wa2[j], s);
    for (int o = 32; o > 0; o >>= 1) s += __shfl_down(s, o, 64);
    if (lane == 0) {
        float v = s + ba2[0];
        w[r] = 1.0f / (1.0f + expf(-v));
    }
}

// ---------------- acc base: acc = root * (1 + sum_active w) ----------------
__global__ __launch_bounds__(256) void k_acc_base(const float* __restrict__ hidden,
                                                  const float* __restrict__ w,
                                                  const int* __restrict__ cnt,
                                                  float* __restrict__ acc) {
    const int row = blockIdx.x;         // b*512+s
    const int t = threadIdx.x;
    const int b = row >> 9;
    __shared__ float coef;
    if (t == 0) {
        float c = 1.f;
        int cb = cnt[b];
        for (int s2 = 0; s2 < NSIM; s2++)
            if (s2 < cb) c += w[s2 * 4 + b];
        coef = c;
    }
    __syncthreads();
    float cf = coef;
    int j = t * 4;
    float4 v = *(const float4*)&hidden[(size_t)row * Hn + j];
    v.x *= cf; v.y *= cf; v.z *= cf; v.w *= cf;
    *(float4*)&acc[(size_t)row * Hn + j] = v;
}

// ---------------- acc sparse: += w*(new - root_row) for last-writer focus rows ----------------
__global__ __launch_bounds__(256) void k_acc_sparse(const float* __restrict__ hidden,
                                                    const float* __restrict__ newbuf,
                                                    const float* __restrict__ w,
                                                    const int* __restrict__ cnt,
                                                    const int* __restrict__ fpos,
                                                    float* __restrict__ acc) {
    const int e = blockIdx.x;           // r*3 + k
    const int r = e / 3, k = e % 3;
    const int sim = r >> 2, b = r & 3;
    if (sim >= cnt[b]) return;
    const int pos = fpos[r * KF + k];
    for (int kp = k + 1; kp < KF; ++kp)
        if (fpos[r * KF + kp] == pos) return;   // not last writer
    const float wv = w[r];
    const float* nrow = newbuf + ((size_t)k * NR + r) * Hn;
    const float* rrow = hidden + ((size_t)b * Sn + pos) * Hn;
    float* arow = acc + ((size_t)b * Sn + pos) * Hn;
    const int t = threadIdx.x;
    for (int j = t; j < Hn; j += 256)
        atomicAdd(&arow[j], wv * (nrow[j] - rrow[j]));
}

// ---------------- launch ----------------
extern "C" void kernel_launch(void* const* d_in, const int* in_sizes, int n_in,
                              void* d_out, int out_size, void* d_ws, size_t ws_size,
                              hipStream_t stream) {
    const float* hidden = (const float*)d_in[0];
    const int* amask = (const int*)d_in[1];
    const float* Wc1 = (const float*)d_in[2];
    const float* bc1 = (const float*)d_in[3];
    const float* Wc2 = (const float*)d_in[4];
    const float* bc2 = (const float*)d_in[5];
    const float* Wp1 = (const float*)d_in[6];
    const float* bp1 = (const float*)d_in[7];
    const float* Wp2 = (const float*)d_in[8];
    const float* bp2 = (const float*)d_in[9];
    const float* Wt1 = (const float*)d_in[10];
    const float* bt1 = (const float*)d_in[11];
    const float* Wt2 = (const float*)d_in[12];
    const float* bt2 = (const float*)d_in[13];
    const float* Wa1 = (const float*)d_in[14];
    const float* ba1 = (const float*)d_in[15];
    const float* Wa2 = (const float*)d_in[16];
    const float* ba2 = (const float*)d_in[17];
    const float* Wg1 = (const float*)d_in[18];
    const float* bg1 = (const float*)d_in[19];
    const float* Wg2 = (const float*)d_in[20];
    const float* bg2 = (const float*)d_in[21];
    float* out = (float*)d_out;

    const int MROWS = Bn * Sn;   // 2048

    // workspace layout (floats)
    float* fw = (float*)d_ws;
    float* P1 = fw;                         // 2048*1024 (p1, reused as G1)
    float* TI = P1 + (size_t)MROWS * Hn;    // 128*2048 (also VA)
    float* T1 = TI + (size_t)NR * 2 * Hn;   // 128*1024 (t1, reused as A1)
    float* NEWB = T1 + (size_t)NR * Hn;     // 3*128*1024
    float* MB = NEWB + (size_t)KF * NR * Hn;// 128*1024
    float* RM = MB + (size_t)NR * Hn;       // 4*1024
    float* FOC = RM + Bn * Hn;              // 2048
    float* WPM = FOC + MROWS;               // 1024
    float* BPM = WPM + Hn;                  // 1
    float* WW = BPM + 1;                    // 128
    int* FPOS = (int*)(WW + NR);            // 128*3
    int* CNT = FPOS + NR * KF;              // 4
    float* ACC = out;                       // acc lives in d_out (2048*1024), rewritten at end

    dim3 blk(256);

    // 1. cls head -> sim_counts
    k_cls<<<dim3(Bn), blk, 0, stream>>>(hidden, Wc1, bc1, Wc2, bc2, CNT);
    // 2. Wp2 row mean + bp2 mean
    k_wp2mean<<<dim3(Hn / 4), blk, 0, stream>>>(Wp2, bp2, WPM, BPM);
    // 3. p1 = gelu(root @ Wp1 + bp1)
    gemm128<1, 0><<<dim3(Hn / 128, MROWS / 128), blk, 0, stream>>>(
        hidden, hidden, Hn, Wp1, bp1, nullptr, P1, MROWS, Hn, Hn);
    // 4. focus scores
    k_focus<<<dim3(MROWS / 4), blk, 0, stream>>>(P1, WPM, BPM, amask, FOC);
    // 5. root mean
    k_rootmean<<<dim3(Bn * Hn / 256), blk, 0, stream>>>(hidden, RM);
    // 6. m init
    k_minit<<<dim3(NR * Hn / 256), blk, 0, stream>>>(RM, MB);
    // 7. gumbel + top-3
    k_gumbel_topk<<<dim3(NR), blk, 0, stream>>>(FOC, FPOS);
    // 8. three focus-update steps
    for (int k = 0; k < KF; ++k) {
        k_ti<<<dim3(NR), blk, 0, stream>>>(MB, hidden, FPOS, k, TI);
        gemm_thin<1><<<dim3(Hn / 128, NR / 16), blk, 0, stream>>>(
            TI, Wt1, bt1, T1, NR, Hn, 2 * Hn);
        gemm_thin<0><<<dim3(Hn / 128, NR / 16), blk, 0, stream>>>(
            T1, Wt2, bt2, NEWB + (size_t)k * NR * Hn, NR, Hn, Hn);
        k_mupdate<<<dim3(NR), blk, 0, stream>>>(MB, NEWB, hidden, FPOS, k);
    }
    // 9. value head -> w
    k_va<<<dim3(NR), blk, 0, stream>>>(RM, MB, TI);
    gemm_thin<1><<<dim3(Hn / 128, NR / 16), blk, 0, stream>>>(
        TI, Wa1, ba1, T1, NR, Hn, 2 * Hn);
    k_val<<<dim3(NR / 4), blk, 0, stream>>>(T1, Wa2, ba2, WW);
    // 10. accumulate
    k_acc_base<<<dim3(MROWS), blk, 0, stream>>>(hidden, WW, CNT, ACC);
    k_acc_sparse<<<dim3(NR * KF), blk, 0, stream>>>(hidden, NEWB, WW, CNT, FPOS, ACC);
    // 11. enhanced = gelu([root|acc] @ Wg1 + bg1) @ Wg2 + bg2 ; out = hidden + enhanced
    gemm128<1, 0><<<dim3(Hn / 128, MROWS / 128), blk, 0, stream>>>(
        hidden, ACC, Hn, Wg1, bg1, nullptr, P1, MROWS, Hn, 2 * Hn);
    gemm128<0, 1><<<dim3(Hn / 128, MROWS / 128), blk, 0, stream>>>(
        P1, P1, Hn, Wg2, bg2, hidden, out, MROWS, Hn, Hn);

    (void)in_sizes; (void)n_in; (void)out_size; (void)ws_size;
}